// Round 1
// baseline (772.691 us; speedup 1.0000x reference)
//
#include <hip/hip_runtime.h>

#define BB 512
#define LL 128
#define MM 127
#define EPS 1e-5f

// ---------------------------------------------------------------- K1: conv1d
// f[m] = [pos[m+1]-pos[m], pos[m]] (6 ch). Both conv directions, folded bn1,
// relu, elementwise max. Batch flip: seq b -> output row B-1-b, pos flip m->M-1-m.
__global__ __launch_bounds__(256) void k1_conv(
    const float* __restrict__ pos, const float* __restrict__ cw,
    const float* __restrict__ cb, const float* __restrict__ g1,
    const float* __restrict__ b1, const float* __restrict__ m1,
    const float* __restrict__ v1, float* __restrict__ xg)
{
  int b = blockIdx.x;
  int tid = threadIdx.x;
  __shared__ float ps[LL * 3];
  __shared__ float fpad[MM + 4][6];
  __shared__ float ws[5 * 6 * 64];
  __shared__ float s1s[64], t1s[64];
  for (int i = tid; i < LL * 3; i += 256) ps[i] = pos[b * LL * 3 + i];
  for (int i = tid; i < 5 * 6 * 64; i += 256) ws[i] = cw[i];
  if (tid < 64) {
    float s = g1[tid] * rsqrtf(v1[tid] + EPS);
    s1s[tid] = s;
    t1s[tid] = (cb[tid] - m1[tid]) * s + b1[tid];
  }
  if (tid < 24) {
    int r = tid / 6, c = tid % 6;
    int rr = (r < 2) ? r : (MM + r);  // rows 0,1,MM+2,MM+3 zeroed
    fpad[rr][c] = 0.f;
  }
  __syncthreads();
  for (int i = tid; i < MM * 6; i += 256) {
    int m = i / 6, c = i % 6;
    float v = (c < 3) ? (ps[(m + 1) * 3 + c] - ps[m * 3 + c]) : ps[m * 3 + c - 3];
    fpad[m + 2][c] = v;
  }
  __syncthreads();
  int orow = BB - 1 - b;
  for (int o = tid; o < MM * 64; o += 256) {
    int m = o >> 6, c = o & 63;
    float af = 0.f, ab = 0.f;
#pragma unroll
    for (int t = 0; t < 5; t++) {
#pragma unroll
      for (int ci = 0; ci < 6; ci++) {
        float wv = ws[(t * 6 + ci) * 64 + c];
        af = fmaf(fpad[m + t][ci], wv, af);       // fwd conv
        ab = fmaf(fpad[m + 4 - t][ci], wv, ab);   // bwd conv
      }
    }
    // max(relu(bn(af)), relu(bn(ab))) = relu(max(af,ab)*s + t)  (s>0)
    float z = fmaxf(af, ab) * s1s[c] + t1s[c];
    xg[(orow * MM + (MM - 1 - m)) * 64 + c] = fmaxf(z, 0.f);
  }
}

// ---------------------------------------------------------------- K2: kNN top-5
// score(j) = sq[j] - 2*dot(x_m, x_j)  (monotone shift of dist). Thread = row.
__global__ __launch_bounds__(128) void k2_knn(
    const float* __restrict__ xg, int* __restrict__ idxb)
{
  int b = blockIdx.x;
  int tid = threadIdx.x;
  __shared__ float xs[MM][64];
  __shared__ float sq[MM];
  const float* src = xg + b * MM * 64;
  for (int i = tid; i < MM * 64; i += 128) xs[i >> 6][i & 63] = src[i];
  __syncthreads();
  float xm[64];
  if (tid < MM) {
    float s = 0.f;
#pragma unroll
    for (int d = 0; d < 64; d++) { xm[d] = xs[tid][d]; s = fmaf(xm[d], xm[d], s); }
    sq[tid] = s;
  }
  __syncthreads();
  if (tid < MM) {
    float bs[5]; int bi[5];
#pragma unroll
    for (int k = 0; k < 5; k++) { bs[k] = 1e30f; bi[k] = 0; }
    for (int j = 0; j < MM; j++) {
      float dot = 0.f;
#pragma unroll
      for (int d = 0; d < 64; d++) dot = fmaf(xm[d], xs[j][d], dot);
      float sc = sq[j] - 2.f * dot;
      if (sc < bs[4]) {
        bs[4] = sc; bi[4] = j;
#pragma unroll
        for (int k = 3; k >= 0; k--) {
          if (bs[k + 1] < bs[k]) {
            float ts = bs[k]; bs[k] = bs[k + 1]; bs[k + 1] = ts;
            int ti = bi[k]; bi[k] = bi[k + 1]; bi[k + 1] = ti;
          }
        }
      }
    }
    int base = (b * MM + tid) * 5;
#pragma unroll
    for (int k = 0; k < 5; k++) idxb[base + k] = bi[k];
  }
}

// ---------------------------------------------------------------- K3: edge MLP
// z_k = xi@(Wt-Wb) + xj@Wb + eb.  Phase A: vv[p] = xs[p]@Wb (each point once).
// Phase B: u[p] = xs[p]@(Wt-Wb); x2[p] = relu(max_k(u+eb+vv[idx_k]))*s2+t2.
__global__ __launch_bounds__(256) void k3_edge(
    const float* __restrict__ xg, const int* __restrict__ idxb,
    const float* __restrict__ ew, const float* __restrict__ eb,
    const float* __restrict__ g2, const float* __restrict__ b2,
    const float* __restrict__ m2, const float* __restrict__ v2,
    float* __restrict__ x2)
{
  int b = blockIdx.x;
  int tid = threadIdx.x;
  int cg = tid & 31, pg = tid >> 5;
  __shared__ float xs[MM][64];     // 32512 B
  __shared__ float wd[64][128];    // 32768 B  (Wt - Wb)
  __shared__ float wb[64][128];    // 32768 B
  __shared__ float vv[MM][128];    // 65024 B   total 163072 <= 160 KiB
  const float* src = xg + b * MM * 64;
  for (int i = tid; i < MM * 64; i += 256) xs[i >> 6][i & 63] = src[i];
  for (int i = tid; i < 64 * 128; i += 256) {
    int d = i >> 7, c = i & 127;
    float top = ew[d * 128 + c];
    float bot = ew[(64 + d) * 128 + c];
    wd[d][c] = top - bot;
    wb[d][c] = bot;
  }
  __syncthreads();
  // Phase A: vv = xs @ wb  (4x4 microtile per thread)
  for (int sw = 0; sw < 4; sw++) {
    int p0 = (pg + sw * 8) * 4;
    float acc[4][4];
#pragma unroll
    for (int i = 0; i < 4; i++)
#pragma unroll
      for (int j = 0; j < 4; j++) acc[i][j] = 0.f;
#pragma unroll 4
    for (int d4 = 0; d4 < 16; d4++) {
      float4 xv[4], wv[4];
#pragma unroll
      for (int pp = 0; pp < 4; pp++) {
        int p = p0 + pp; if (p > MM - 1) p = MM - 1;
        xv[pp] = *reinterpret_cast<const float4*>(&xs[p][d4 * 4]);
      }
#pragma unroll
      for (int dd = 0; dd < 4; dd++)
        wv[dd] = *reinterpret_cast<const float4*>(&wb[d4 * 4 + dd][cg * 4]);
#pragma unroll
      for (int pp = 0; pp < 4; pp++) {
        float xa[4] = {xv[pp].x, xv[pp].y, xv[pp].z, xv[pp].w};
#pragma unroll
        for (int dd = 0; dd < 4; dd++) {
          acc[pp][0] = fmaf(xa[dd], wv[dd].x, acc[pp][0]);
          acc[pp][1] = fmaf(xa[dd], wv[dd].y, acc[pp][1]);
          acc[pp][2] = fmaf(xa[dd], wv[dd].z, acc[pp][2]);
          acc[pp][3] = fmaf(xa[dd], wv[dd].w, acc[pp][3]);
        }
      }
    }
#pragma unroll
    for (int pp = 0; pp < 4; pp++) {
      int p = p0 + pp;
      if (p < MM) {
        vv[p][cg * 4 + 0] = acc[pp][0];
        vv[p][cg * 4 + 1] = acc[pp][1];
        vv[p][cg * 4 + 2] = acc[pp][2];
        vv[p][cg * 4 + 3] = acc[pp][3];
      }
    }
  }
  __syncthreads();
  float s2a[4], t2a[4], eba[4];
#pragma unroll
  for (int cc = 0; cc < 4; cc++) {
    int c = cg * 4 + cc;
    float s = g2[c] * rsqrtf(v2[c] + EPS);
    s2a[cc] = s;
    t2a[cc] = b2[c] - m2[c] * s;
    eba[cc] = eb[c];
  }
  // Phase B: u + combine
  for (int sw = 0; sw < 4; sw++) {
    int p0 = (pg + sw * 8) * 4;
    float acc[4][4];
#pragma unroll
    for (int i = 0; i < 4; i++)
#pragma unroll
      for (int j = 0; j < 4; j++) acc[i][j] = 0.f;
#pragma unroll 4
    for (int d4 = 0; d4 < 16; d4++) {
      float4 xv[4], wv[4];
#pragma unroll
      for (int pp = 0; pp < 4; pp++) {
        int p = p0 + pp; if (p > MM - 1) p = MM - 1;
        xv[pp] = *reinterpret_cast<const float4*>(&xs[p][d4 * 4]);
      }
#pragma unroll
      for (int dd = 0; dd < 4; dd++)
        wv[dd] = *reinterpret_cast<const float4*>(&wd[d4 * 4 + dd][cg * 4]);
#pragma unroll
      for (int pp = 0; pp < 4; pp++) {
        float xa[4] = {xv[pp].x, xv[pp].y, xv[pp].z, xv[pp].w};
#pragma unroll
        for (int dd = 0; dd < 4; dd++) {
          acc[pp][0] = fmaf(xa[dd], wv[dd].x, acc[pp][0]);
          acc[pp][1] = fmaf(xa[dd], wv[dd].y, acc[pp][1]);
          acc[pp][2] = fmaf(xa[dd], wv[dd].z, acc[pp][2]);
          acc[pp][3] = fmaf(xa[dd], wv[dd].w, acc[pp][3]);
        }
      }
    }
#pragma unroll
    for (int pp = 0; pp < 4; pp++) {
      int p = p0 + pp;
      if (p >= MM) continue;
      const int* ip = idxb + (b * MM + p) * 5;
      float u0 = acc[pp][0] + eba[0], u1 = acc[pp][1] + eba[1];
      float u2 = acc[pp][2] + eba[2], u3 = acc[pp][3] + eba[3];
      float mx0 = -1e30f, mx1 = -1e30f, mx2 = -1e30f, mx3 = -1e30f;
#pragma unroll
      for (int k = 0; k < 5; k++) {
        int j = ip[k];
        float4 vj = *reinterpret_cast<const float4*>(&vv[j][cg * 4]);
        mx0 = fmaxf(mx0, u0 + vj.x);
        mx1 = fmaxf(mx1, u1 + vj.y);
        mx2 = fmaxf(mx2, u2 + vj.z);
        mx3 = fmaxf(mx3, u3 + vj.w);
      }
      float4 o;
      o.x = fmaxf(mx0, 0.f) * s2a[0] + t2a[0];
      o.y = fmaxf(mx1, 0.f) * s2a[1] + t2a[1];
      o.z = fmaxf(mx2, 0.f) * s2a[2] + t2a[2];
      o.w = fmaxf(mx3, 0.f) * s2a[3] + t2a[3];
      *reinterpret_cast<float4*>(&x2[(b * MM + p) * 128 + cg * 4]) = o;
    }
  }
}

// ---------------------------------------------------------------- K4: lin1 + max over M
// block = (b, coltile of 128). h = [xg | x2] (192). W tile in LDS, 64-row sweeps,
// per-thread 8p x 4c microtile, running relu-max, bn3 after reduction.
__global__ __launch_bounds__(256) void k4_lin1(
    const float* __restrict__ xg, const float* __restrict__ x2,
    const float* __restrict__ lw, const float* __restrict__ lb,
    const float* __restrict__ g3, const float* __restrict__ b3,
    const float* __restrict__ m3, const float* __restrict__ v3,
    float* __restrict__ gout)
{
  int bid = blockIdx.x;
  int b = bid >> 3, ct = bid & 7;
  int tid = threadIdx.x;
  int cg = tid & 31, pg = tid >> 5;
  __shared__ float wt[192][128];   // 98304 B
  __shared__ float hin[64][192];   // 49152 B
  __shared__ float red[8][128];    //  4096 B
  for (int i4 = tid; i4 < 192 * 32; i4 += 256) {
    int d = i4 >> 5, c4 = i4 & 31;
    *reinterpret_cast<float4*>(&wt[d][c4 * 4]) =
        *reinterpret_cast<const float4*>(&lw[d * 1024 + ct * 128 + c4 * 4]);
  }
  float lbv[4], s3a[4], t3a[4];
#pragma unroll
  for (int cc = 0; cc < 4; cc++) {
    int c = ct * 128 + cg * 4 + cc;
    lbv[cc] = lb[c];
    float s = g3[c] * rsqrtf(v3[c] + EPS);
    s3a[cc] = s;
    t3a[cc] = b3[c] - m3[c] * s;
  }
  float rmax[4] = {0.f, 0.f, 0.f, 0.f};
  for (int sw = 0; sw < 2; sw++) {
    __syncthreads();
    for (int i4 = tid; i4 < 64 * 48; i4 += 256) {
      int r = i4 / 48, off = i4 % 48;
      int p = sw * 64 + r;
      float4 val;
      if (p < MM) {
        if (off < 16)
          val = *reinterpret_cast<const float4*>(&xg[(b * MM + p) * 64 + off * 4]);
        else
          val = *reinterpret_cast<const float4*>(&x2[(b * MM + p) * 128 + (off - 16) * 4]);
      } else {
        val = make_float4(0.f, 0.f, 0.f, 0.f);
      }
      *reinterpret_cast<float4*>(&hin[r][off * 4]) = val;
    }
    __syncthreads();
    float acc[8][4];
#pragma unroll
    for (int pp = 0; pp < 8; pp++)
#pragma unroll
      for (int cc = 0; cc < 4; cc++) acc[pp][cc] = 0.f;
    for (int d4 = 0; d4 < 48; d4++) {
      float4 wv[4];
#pragma unroll
      for (int dd = 0; dd < 4; dd++)
        wv[dd] = *reinterpret_cast<const float4*>(&wt[d4 * 4 + dd][cg * 4]);
#pragma unroll
      for (int pp = 0; pp < 8; pp++) {
        float4 hv = *reinterpret_cast<const float4*>(&hin[pg * 8 + pp][d4 * 4]);
        float ha[4] = {hv.x, hv.y, hv.z, hv.w};
#pragma unroll
        for (int dd = 0; dd < 4; dd++) {
          acc[pp][0] = fmaf(ha[dd], wv[dd].x, acc[pp][0]);
          acc[pp][1] = fmaf(ha[dd], wv[dd].y, acc[pp][1]);
          acc[pp][2] = fmaf(ha[dd], wv[dd].z, acc[pp][2]);
          acc[pp][3] = fmaf(ha[dd], wv[dd].w, acc[pp][3]);
        }
      }
    }
#pragma unroll
    for (int pp = 0; pp < 8; pp++) {
      int p = sw * 64 + pg * 8 + pp;
      if (p < MM) {
#pragma unroll
        for (int cc = 0; cc < 4; cc++) {
          float z = fmaxf(acc[pp][cc] + lbv[cc], 0.f);
          rmax[cc] = fmaxf(rmax[cc], z);
        }
      }
    }
  }
#pragma unroll
  for (int cc = 0; cc < 4; cc++) red[pg][cg * 4 + cc] = rmax[cc];
  __syncthreads();
  if (pg == 0) {
#pragma unroll
    for (int cc = 0; cc < 4; cc++) {
      int c = cg * 4 + cc;
      float mv = red[0][c];
#pragma unroll
      for (int r = 1; r < 8; r++) mv = fmaxf(mv, red[r][c]);
      gout[b * 1024 + ct * 128 + c] = mv * s3a[cc] + t3a[cc];
    }
  }
}

// ---------------------------------------------------------------- K5: head MLP layers
// out = bn(relu(in @ W + bias)). 4 rows x 128 cols per block, 2 rows per thread.
__global__ __launch_bounds__(256) void k5_mlp(
    const float* __restrict__ in, const float* __restrict__ w,
    const float* __restrict__ bias, const float* __restrict__ gg,
    const float* __restrict__ bbp, const float* __restrict__ mmp,
    const float* __restrict__ vvp, float* __restrict__ out,
    int K, int N, int ctiles)
{
  int bid = blockIdx.x;
  int rg = bid / ctiles, ct = bid % ctiles;
  int tid = threadIdx.x;
  int c = tid & 127, rh = tid >> 7;
  int col = ct * 128 + c;
  extern __shared__ float grows[];  // [4][K]
  for (int i = tid; i < 4 * K; i += 256) grows[i] = in[rg * 4 * K + i];
  __syncthreads();
  float acc0 = 0.f, acc1 = 0.f;
  for (int d4 = 0; d4 < K / 4; d4++) {
    float4 ga = *reinterpret_cast<const float4*>(&grows[rh * K + d4 * 4]);
    float4 gb = *reinterpret_cast<const float4*>(&grows[(rh + 2) * K + d4 * 4]);
    float gaa[4] = {ga.x, ga.y, ga.z, ga.w};
    float gba[4] = {gb.x, gb.y, gb.z, gb.w};
#pragma unroll
    for (int dd = 0; dd < 4; dd++) {
      float wv = w[(d4 * 4 + dd) * N + col];
      acc0 = fmaf(gaa[dd], wv, acc0);
      acc1 = fmaf(gba[dd], wv, acc1);
    }
  }
  float s = gg[col] * rsqrtf(vvp[col] + EPS);
  float t = bbp[col] - mmp[col] * s;
  float bv = bias[col];
  int r0 = rg * 4;
  out[(r0 + rh) * N + col] = fmaxf(acc0 + bv, 0.f) * s + t;
  out[(r0 + rh + 2) * N + col] = fmaxf(acc1 + bv, 0.f) * s + t;
}

// ---------------------------------------------------------------- K5c: final 256->2
__global__ __launch_bounds__(256) void k5c_out(
    const float* __restrict__ c2, const float* __restrict__ ow,
    const float* __restrict__ ob, float* __restrict__ out)
{
  int t = blockIdx.x * 256 + threadIdx.x;  // 0..1023
  int r = t >> 1, c = t & 1;
  float acc = 0.f;
  for (int d = 0; d < 256; d++) acc = fmaf(c2[r * 256 + d], ow[d * 2 + c], acc);
  out[t] = acc + ob[c];
}

extern "C" void kernel_launch(void* const* d_in, const int* in_sizes, int n_in,
                              void* d_out, int out_size, void* d_ws, size_t ws_size,
                              hipStream_t stream)
{
  const float* pos = (const float*)d_in[0];
  const float* cw  = (const float*)d_in[4];
  const float* cb  = (const float*)d_in[5];
  const float* g1  = (const float*)d_in[6];
  const float* b1  = (const float*)d_in[7];
  const float* m1  = (const float*)d_in[8];
  const float* v1  = (const float*)d_in[9];
  const float* ew  = (const float*)d_in[10];
  const float* eb  = (const float*)d_in[11];
  const float* g2  = (const float*)d_in[12];
  const float* b2  = (const float*)d_in[13];
  const float* m2  = (const float*)d_in[14];
  const float* v2  = (const float*)d_in[15];
  const float* lw  = (const float*)d_in[16];
  const float* lb  = (const float*)d_in[17];
  const float* g3  = (const float*)d_in[18];
  const float* b3  = (const float*)d_in[19];
  const float* m3  = (const float*)d_in[20];
  const float* v3  = (const float*)d_in[21];
  const float* m1w = (const float*)d_in[22];
  const float* m1b = (const float*)d_in[23];
  const float* g4  = (const float*)d_in[24];
  const float* b4  = (const float*)d_in[25];
  const float* m4  = (const float*)d_in[26];
  const float* v4  = (const float*)d_in[27];
  const float* m2w = (const float*)d_in[28];
  const float* m2b = (const float*)d_in[29];
  const float* g5  = (const float*)d_in[30];
  const float* b5  = (const float*)d_in[31];
  const float* m5  = (const float*)d_in[32];
  const float* v5  = (const float*)d_in[33];
  const float* ow  = (const float*)d_in[34];
  const float* ob  = (const float*)d_in[35];

  char* ws = (char*)d_ws;
  float* xg   = (float*)(ws);              // 512*127*64  f32 = 16,646,144 B
  float* x2   = (float*)(ws + 16646144);   // 512*127*128 f32 = 33,292,288 B
  int*   idxb = (int*)  (ws + 49938432);   // 512*127*5   i32 =  1,300,480 B
  float* gbuf = (float*)(ws + 51238912);   // 512*1024    f32 =  2,097,152 B
  float* c1   = (float*)(ws + 53336064);   // 512*512     f32 =  1,048,576 B
  float* c2   = (float*)(ws + 54384640);   // 512*256     f32 =    524,288 B

  hipLaunchKernelGGL(k1_conv, dim3(512), dim3(256), 0, stream,
                     pos, cw, cb, g1, b1, m1, v1, xg);
  hipLaunchKernelGGL(k2_knn, dim3(512), dim3(128), 0, stream, xg, idxb);
  hipLaunchKernelGGL(k3_edge, dim3(512), dim3(256), 0, stream,
                     xg, idxb, ew, eb, g2, b2, m2, v2, x2);
  hipLaunchKernelGGL(k4_lin1, dim3(4096), dim3(256), 0, stream,
                     xg, x2, lw, lb, g3, b3, m3, v3, gbuf);
  hipLaunchKernelGGL(k5_mlp, dim3(512), dim3(256), 4 * 1024 * 4, stream,
                     gbuf, m1w, m1b, g4, b4, m4, v4, c1, 1024, 512, 4);
  hipLaunchKernelGGL(k5_mlp, dim3(256), dim3(256), 4 * 512 * 4, stream,
                     c1, m2w, m2b, g5, b5, m5, v5, c2, 512, 256, 2);
  hipLaunchKernelGGL(k5c_out, dim3(4), dim3(256), 0, stream,
                     c2, ow, ob, (float*)d_out);
}

// Round 2
// 291.903 us; speedup vs baseline: 2.6471x; 2.6471x over previous
//
#include <hip/hip_runtime.h>

#define BB 512
#define LL 128
#define MM 127
#define EPS 1e-5f

typedef _Float16 half4 __attribute__((ext_vector_type(4)));
typedef _Float16 half8 __attribute__((ext_vector_type(8)));
typedef float f32x16 __attribute__((ext_vector_type(16)));

// hb layout: per batch b: 128 rows x 192 ch fp16, row pitch 384 B,
// in-row byte offset = (2*ch) ^ ((row&7)<<4)   (XOR swizzle, G4)
#define HB_PITCH 384
#define HB_BATCH 49152

// ---------------------------------------------------------------- K0: transpose lin1_w
// lwT[col][k] fp16, pre-swizzled like hb. One-time per launch (~786 KB).
__global__ __launch_bounds__(256) void k0_prep(
    const float* __restrict__ lw, char* __restrict__ lwT)
{
  int c0 = blockIdx.x * 32;
  int tid = threadIdx.x;
  __shared__ float wcol[192][32];
  for (int i = tid; i < 192 * 32; i += 256) {
    int k = i >> 5, c = i & 31;
    wcol[k][c] = lw[k * 1024 + c0 + c];
  }
  __syncthreads();
  for (int j = tid; j < 768; j += 256) {
    int kg = j >> 5, c = j & 31;   // kg 0..23, c 0..31
    half8 v;
#pragma unroll
    for (int jj = 0; jj < 8; jj++) v[jj] = (_Float16)wcol[kg * 8 + jj][c];
    int cc = c0 + c;
    *(half8*)(lwT + cc * HB_PITCH + ((kg * 16) ^ ((cc & 7) << 4))) = v;
  }
}

// ---------------------------------------------------------------- K1: conv1d
__global__ __launch_bounds__(256) void k1_conv(
    const float* __restrict__ pos, const float* __restrict__ cw,
    const float* __restrict__ cb, const float* __restrict__ g1,
    const float* __restrict__ b1, const float* __restrict__ m1,
    const float* __restrict__ v1, float* __restrict__ xg,
    char* __restrict__ hb)
{
  int b = blockIdx.x;
  int tid = threadIdx.x;
  __shared__ float ps[LL * 3];
  __shared__ float fpad[MM + 4][6];
  __shared__ float ws[5 * 6 * 64];
  __shared__ float s1s[64], t1s[64];
  for (int i = tid; i < LL * 3; i += 256) ps[i] = pos[b * LL * 3 + i];
  for (int i = tid; i < 5 * 6 * 64; i += 256) ws[i] = cw[i];
  if (tid < 64) {
    float s = g1[tid] * rsqrtf(v1[tid] + EPS);
    s1s[tid] = s;
    t1s[tid] = (cb[tid] - m1[tid]) * s + b1[tid];
  }
  if (tid < 24) {
    int r = tid / 6, c = tid % 6;
    int rr = (r < 2) ? r : (MM + r);
    fpad[rr][c] = 0.f;
  }
  __syncthreads();
  for (int i = tid; i < MM * 6; i += 256) {
    int m = i / 6, c = i % 6;
    float v = (c < 3) ? (ps[(m + 1) * 3 + c] - ps[m * 3 + c]) : ps[m * 3 + c - 3];
    fpad[m + 2][c] = v;
  }
  __syncthreads();
  int orow = BB - 1 - b;
  char* hbb = hb + (size_t)orow * HB_BATCH;
  // zero fp16 pad row 127, ch 0..63 region (bytes [0,128))
  if (tid < 8) *(float4*)(hbb + 127 * HB_PITCH + tid * 16) = make_float4(0.f, 0.f, 0.f, 0.f);
  for (int o = tid; o < MM * 64; o += 256) {
    int m = o >> 6, c = o & 63;
    float af = 0.f, ab = 0.f;
#pragma unroll
    for (int t = 0; t < 5; t++) {
#pragma unroll
      for (int ci = 0; ci < 6; ci++) {
        float wv = ws[(t * 6 + ci) * 64 + c];
        af = fmaf(fpad[m + t][ci], wv, af);
        ab = fmaf(fpad[m + 4 - t][ci], wv, ab);
      }
    }
    float z = fmaxf(af, ab) * s1s[c] + t1s[c];
    float xv = fmaxf(z, 0.f);
    int p = MM - 1 - m;
    xg[(orow * MM + p) * 64 + c] = xv;
    *(_Float16*)(hbb + p * HB_PITCH + ((2 * c) ^ ((p & 7) << 4))) = (_Float16)xv;
  }
}

// ---------------------------------------------------------------- K2: kNN top-5
__global__ __launch_bounds__(128) void k2_knn(
    const float* __restrict__ xg, int* __restrict__ idxb)
{
  int b = blockIdx.x;
  int tid = threadIdx.x;
  __shared__ float xs[MM][64];
  __shared__ float sq[MM];
  const float* src = xg + b * MM * 64;
  for (int i = tid; i < MM * 64; i += 128) xs[i >> 6][i & 63] = src[i];
  __syncthreads();
  float xm[64];
  if (tid < MM) {
    float s = 0.f;
#pragma unroll
    for (int d = 0; d < 64; d++) { xm[d] = xs[tid][d]; s = fmaf(xm[d], xm[d], s); }
    sq[tid] = s;
  }
  __syncthreads();
  if (tid < MM) {
    float bs[5]; int bi[5];
#pragma unroll
    for (int k = 0; k < 5; k++) { bs[k] = 1e30f; bi[k] = 0; }
    for (int j = 0; j < MM; j++) {
      float dot = 0.f;
#pragma unroll
      for (int d = 0; d < 64; d++) dot = fmaf(xm[d], xs[j][d], dot);
      float sc = sq[j] - 2.f * dot;
      if (sc < bs[4]) {
        bs[4] = sc; bi[4] = j;
#pragma unroll
        for (int k = 3; k >= 0; k--) {
          if (bs[k + 1] < bs[k]) {
            float ts = bs[k]; bs[k] = bs[k + 1]; bs[k + 1] = ts;
            int ti = bi[k]; bi[k] = bi[k + 1]; bi[k + 1] = ti;
          }
        }
      }
    }
    int base = (b * MM + tid) * 5;
#pragma unroll
    for (int k = 0; k < 5; k++) idxb[base + k] = bi[k];
  }
}

// ---------------------------------------------------------------- K3: edge MLP
// Output goes straight into hb (fp16, swizzled) channels 64..191.
__global__ __launch_bounds__(256) void k3_edge(
    const float* __restrict__ xg, const int* __restrict__ idxb,
    const float* __restrict__ ew, const float* __restrict__ eb,
    const float* __restrict__ g2, const float* __restrict__ b2,
    const float* __restrict__ m2, const float* __restrict__ v2,
    char* __restrict__ hb)
{
  int b = blockIdx.x;
  int tid = threadIdx.x;
  int cg = tid & 31, pg = tid >> 5;
  __shared__ float xs[MM][64];
  __shared__ float wd[64][128];
  __shared__ float wb[64][128];
  __shared__ float vv[MM][128];
  const float* src = xg + b * MM * 64;
  char* hbb = hb + (size_t)b * HB_BATCH;
  // zero fp16 pad row 127, ch 64..191 region (bytes [128,384))
  if (tid < 16) *(float4*)(hbb + 127 * HB_PITCH + 128 + tid * 16) = make_float4(0.f, 0.f, 0.f, 0.f);
  for (int i = tid; i < MM * 64; i += 256) xs[i >> 6][i & 63] = src[i];
  for (int i = tid; i < 64 * 128; i += 256) {
    int d = i >> 7, c = i & 127;
    float top = ew[d * 128 + c];
    float bot = ew[(64 + d) * 128 + c];
    wd[d][c] = top - bot;
    wb[d][c] = bot;
  }
  __syncthreads();
  for (int sw = 0; sw < 4; sw++) {
    int p0 = (pg + sw * 8) * 4;
    float acc[4][4];
#pragma unroll
    for (int i = 0; i < 4; i++)
#pragma unroll
      for (int j = 0; j < 4; j++) acc[i][j] = 0.f;
#pragma unroll 4
    for (int d4 = 0; d4 < 16; d4++) {
      float4 xv[4], wv[4];
#pragma unroll
      for (int pp = 0; pp < 4; pp++) {
        int p = p0 + pp; if (p > MM - 1) p = MM - 1;
        xv[pp] = *reinterpret_cast<const float4*>(&xs[p][d4 * 4]);
      }
#pragma unroll
      for (int dd = 0; dd < 4; dd++)
        wv[dd] = *reinterpret_cast<const float4*>(&wb[d4 * 4 + dd][cg * 4]);
#pragma unroll
      for (int pp = 0; pp < 4; pp++) {
        float xa[4] = {xv[pp].x, xv[pp].y, xv[pp].z, xv[pp].w};
#pragma unroll
        for (int dd = 0; dd < 4; dd++) {
          acc[pp][0] = fmaf(xa[dd], wv[dd].x, acc[pp][0]);
          acc[pp][1] = fmaf(xa[dd], wv[dd].y, acc[pp][1]);
          acc[pp][2] = fmaf(xa[dd], wv[dd].z, acc[pp][2]);
          acc[pp][3] = fmaf(xa[dd], wv[dd].w, acc[pp][3]);
        }
      }
    }
#pragma unroll
    for (int pp = 0; pp < 4; pp++) {
      int p = p0 + pp;
      if (p < MM) {
        vv[p][cg * 4 + 0] = acc[pp][0];
        vv[p][cg * 4 + 1] = acc[pp][1];
        vv[p][cg * 4 + 2] = acc[pp][2];
        vv[p][cg * 4 + 3] = acc[pp][3];
      }
    }
  }
  __syncthreads();
  float s2a[4], t2a[4], eba[4];
#pragma unroll
  for (int cc = 0; cc < 4; cc++) {
    int c = cg * 4 + cc;
    float s = g2[c] * rsqrtf(v2[c] + EPS);
    s2a[cc] = s;
    t2a[cc] = b2[c] - m2[c] * s;
    eba[cc] = eb[c];
  }
  for (int sw = 0; sw < 4; sw++) {
    int p0 = (pg + sw * 8) * 4;
    float acc[4][4];
#pragma unroll
    for (int i = 0; i < 4; i++)
#pragma unroll
      for (int j = 0; j < 4; j++) acc[i][j] = 0.f;
#pragma unroll 4
    for (int d4 = 0; d4 < 16; d4++) {
      float4 xv[4], wv[4];
#pragma unroll
      for (int pp = 0; pp < 4; pp++) {
        int p = p0 + pp; if (p > MM - 1) p = MM - 1;
        xv[pp] = *reinterpret_cast<const float4*>(&xs[p][d4 * 4]);
      }
#pragma unroll
      for (int dd = 0; dd < 4; dd++)
        wv[dd] = *reinterpret_cast<const float4*>(&wd[d4 * 4 + dd][cg * 4]);
#pragma unroll
      for (int pp = 0; pp < 4; pp++) {
        float xa[4] = {xv[pp].x, xv[pp].y, xv[pp].z, xv[pp].w};
#pragma unroll
        for (int dd = 0; dd < 4; dd++) {
          acc[pp][0] = fmaf(xa[dd], wv[dd].x, acc[pp][0]);
          acc[pp][1] = fmaf(xa[dd], wv[dd].y, acc[pp][1]);
          acc[pp][2] = fmaf(xa[dd], wv[dd].z, acc[pp][2]);
          acc[pp][3] = fmaf(xa[dd], wv[dd].w, acc[pp][3]);
        }
      }
    }
#pragma unroll
    for (int pp = 0; pp < 4; pp++) {
      int p = p0 + pp;
      if (p >= MM) continue;
      const int* ip = idxb + (b * MM + p) * 5;
      float u0 = acc[pp][0] + eba[0], u1 = acc[pp][1] + eba[1];
      float u2 = acc[pp][2] + eba[2], u3 = acc[pp][3] + eba[3];
      float mx0 = -1e30f, mx1 = -1e30f, mx2 = -1e30f, mx3 = -1e30f;
#pragma unroll
      for (int k = 0; k < 5; k++) {
        int j = ip[k];
        float4 vj = *reinterpret_cast<const float4*>(&vv[j][cg * 4]);
        mx0 = fmaxf(mx0, u0 + vj.x);
        mx1 = fmaxf(mx1, u1 + vj.y);
        mx2 = fmaxf(mx2, u2 + vj.z);
        mx3 = fmaxf(mx3, u3 + vj.w);
      }
      half4 o;
      o[0] = (_Float16)(fmaxf(mx0, 0.f) * s2a[0] + t2a[0]);
      o[1] = (_Float16)(fmaxf(mx1, 0.f) * s2a[1] + t2a[1]);
      o[2] = (_Float16)(fmaxf(mx2, 0.f) * s2a[2] + t2a[2]);
      o[3] = (_Float16)(fmaxf(mx3, 0.f) * s2a[3] + t2a[3]);
      // channels 64 + cg*4 .. +4 -> bytes 128 + 8*cg, swizzled (stays 8B aligned)
      *(half4*)(hbb + p * HB_PITCH + ((128 + 8 * cg) ^ ((p & 7) << 4))) = o;
    }
  }
}

// ---------------------------------------------------------------- K4: lin1 via MFMA + max over M
// One block per b. A = hb[b] (128x192 fp16) resident in LDS, 48 A-frags held in
// registers. B = lwT streamed in 8 chunks of 128 cols, double-buffered, async
// split (issue loads before MFMA phase, ds_write after). 32x32x16 f16 MFMA.
// Epilogue: relu(z+bias) -> masked max over rows -> shfl -> bn3 -> gbuf.
__global__ __launch_bounds__(256, 1) void k4_lin1(
    const char* __restrict__ hb, const char* __restrict__ lwT,
    const float* __restrict__ lb, const float* __restrict__ g3,
    const float* __restrict__ b3, const float* __restrict__ m3,
    const float* __restrict__ v3, float* __restrict__ gout)
{
  int b = blockIdx.x;
  int tid = threadIdx.x;
  int w = tid >> 6, l = tid & 63;
  int lo = l & 31, hi = l >> 5;
  int swz = (l & 7) << 4;
  __shared__ __align__(16) char sA[HB_BATCH];
  __shared__ __align__(16) char sB[2][HB_BATCH];

  // stage A (linear copy; data pre-swizzled in global)
  {
    const char* gA = hb + (size_t)b * HB_BATCH;
    float4 t[12];
#pragma unroll
    for (int i = 0; i < 12; i++) t[i] = *(const float4*)(gA + (i * 256 + tid) * 16);
#pragma unroll
    for (int i = 0; i < 12; i++) *(float4*)(sA + (i * 256 + tid) * 16) = t[i];
  }
  // stage B chunk 0
  {
    float4 t[12];
#pragma unroll
    for (int i = 0; i < 12; i++) t[i] = *(const float4*)(lwT + (i * 256 + tid) * 16);
#pragma unroll
    for (int i = 0; i < 12; i++) *(float4*)(sB[0] + (i * 256 + tid) * 16) = t[i];
  }
  __syncthreads();

  // A-fragments: af[rt][ks]: row = rt*32+lo, k bytes (ks*32 + hi*16) ^ swz
  half8 af[4][12];
#pragma unroll
  for (int rt = 0; rt < 4; rt++) {
    const char* rbase = sA + (rt * 32 + lo) * HB_PITCH;
#pragma unroll
    for (int ks = 0; ks < 12; ks++)
      af[rt][ks] = *(const half8*)(rbase + ((ks * 32 + hi * 16) ^ swz));
  }

  int colc = w * 32 + lo;  // column within 128-col chunk; (colc&7)==(l&7)
  float4 pre[12];
  for (int c = 0; c < 8; c++) {
    // T14 async split: issue next chunk's global loads before MFMA phase
    if (c < 7) {
      const char* gB = lwT + (size_t)(c + 1) * HB_BATCH;
#pragma unroll
      for (int i = 0; i < 12; i++) pre[i] = *(const float4*)(gB + (i * 256 + tid) * 16);
    }
    f32x16 acc[4];
#pragma unroll
    for (int rt = 0; rt < 4; rt++)
#pragma unroll
      for (int r = 0; r < 16; r++) acc[rt][r] = 0.f;
    const char* cbase = sB[c & 1] + colc * HB_PITCH;
#pragma unroll
    for (int ks = 0; ks < 12; ks++) {
      half8 bf = *(const half8*)(cbase + ((ks * 32 + hi * 16) ^ swz));
#pragma unroll
      for (int rt = 0; rt < 4; rt++)
        acc[rt] = __builtin_amdgcn_mfma_f32_32x32x16_f16(af[rt][ks], bf, acc[rt], 0, 0, 0);
    }
    // epilogue: relu(z+bias), max over rows (mask global row 127), bn3
    int col = c * 128 + colc;
    float bias = lb[col];
    float rm = 0.f;
#pragma unroll
    for (int rt = 0; rt < 4; rt++) {
#pragma unroll
      for (int r = 0; r < 16; r++) {
        float v = fmaxf(acc[rt][r] + bias, 0.f);
        if (rt == 3 && r == 15) v = hi ? 0.f : v;  // global row 127 = pad
        rm = fmaxf(rm, v);
      }
    }
    rm = fmaxf(rm, __shfl_xor(rm, 32));
    if (hi == 0) {
      float s = g3[col] * rsqrtf(v3[col] + EPS);
      float t = b3[col] - m3[col] * s;
      gout[b * 1024 + col] = rm * s + t;
    }
    // late ds_write of prefetched chunk (buffer last read in iter c-1, safe)
    if (c < 7) {
      char* db = sB[(c + 1) & 1];
#pragma unroll
      for (int i = 0; i < 12; i++) *(float4*)(db + (i * 256 + tid) * 16) = pre[i];
    }
    __syncthreads();
  }
}

// ---------------------------------------------------------------- K5: head MLP layers
__global__ __launch_bounds__(256) void k5_mlp(
    const float* __restrict__ in, const float* __restrict__ w,
    const float* __restrict__ bias, const float* __restrict__ gg,
    const float* __restrict__ bbp, const float* __restrict__ mmp,
    const float* __restrict__ vvp, float* __restrict__ out,
    int K, int N, int ctiles)
{
  int bid = blockIdx.x;
  int rg = bid / ctiles, ct = bid % ctiles;
  int tid = threadIdx.x;
  int c = tid & 127, rh = tid >> 7;
  int col = ct * 128 + c;
  extern __shared__ float grows[];
  for (int i = tid; i < 4 * K; i += 256) grows[i] = in[rg * 4 * K + i];
  __syncthreads();
  float acc0 = 0.f, acc1 = 0.f;
  for (int d4 = 0; d4 < K / 4; d4++) {
    float4 ga = *reinterpret_cast<const float4*>(&grows[rh * K + d4 * 4]);
    float4 gb = *reinterpret_cast<const float4*>(&grows[(rh + 2) * K + d4 * 4]);
    float gaa[4] = {ga.x, ga.y, ga.z, ga.w};
    float gba[4] = {gb.x, gb.y, gb.z, gb.w};
#pragma unroll
    for (int dd = 0; dd < 4; dd++) {
      float wv = w[(d4 * 4 + dd) * N + col];
      acc0 = fmaf(gaa[dd], wv, acc0);
      acc1 = fmaf(gba[dd], wv, acc1);
    }
  }
  float s = gg[col] * rsqrtf(vvp[col] + EPS);
  float t = bbp[col] - mmp[col] * s;
  float bv = bias[col];
  int r0 = rg * 4;
  out[(r0 + rh) * N + col] = fmaxf(acc0 + bv, 0.f) * s + t;
  out[(r0 + rh + 2) * N + col] = fmaxf(acc1 + bv, 0.f) * s + t;
}

// ---------------------------------------------------------------- K5c: final 256->2
__global__ __launch_bounds__(256) void k5c_out(
    const float* __restrict__ c2, const float* __restrict__ ow,
    const float* __restrict__ ob, float* __restrict__ out)
{
  int t = blockIdx.x * 256 + threadIdx.x;
  int r = t >> 1, c = t & 1;
  float acc = 0.f;
  for (int d = 0; d < 256; d++) acc = fmaf(c2[r * 256 + d], ow[d * 2 + c], acc);
  out[t] = acc + ob[c];
}

extern "C" void kernel_launch(void* const* d_in, const int* in_sizes, int n_in,
                              void* d_out, int out_size, void* d_ws, size_t ws_size,
                              hipStream_t stream)
{
  const float* pos = (const float*)d_in[0];
  const float* cw  = (const float*)d_in[4];
  const float* cb  = (const float*)d_in[5];
  const float* g1  = (const float*)d_in[6];
  const float* b1  = (const float*)d_in[7];
  const float* m1  = (const float*)d_in[8];
  const float* v1  = (const float*)d_in[9];
  const float* ew  = (const float*)d_in[10];
  const float* eb  = (const float*)d_in[11];
  const float* g2  = (const float*)d_in[12];
  const float* b2  = (const float*)d_in[13];
  const float* m2  = (const float*)d_in[14];
  const float* v2  = (const float*)d_in[15];
  const float* lw  = (const float*)d_in[16];
  const float* lb  = (const float*)d_in[17];
  const float* g3  = (const float*)d_in[18];
  const float* b3  = (const float*)d_in[19];
  const float* m3  = (const float*)d_in[20];
  const float* v3  = (const float*)d_in[21];
  const float* m1w = (const float*)d_in[22];
  const float* m1b = (const float*)d_in[23];
  const float* g4  = (const float*)d_in[24];
  const float* b4  = (const float*)d_in[25];
  const float* m4  = (const float*)d_in[26];
  const float* v4  = (const float*)d_in[27];
  const float* m2w = (const float*)d_in[28];
  const float* m2b = (const float*)d_in[29];
  const float* g5  = (const float*)d_in[30];
  const float* b5  = (const float*)d_in[31];
  const float* m5  = (const float*)d_in[32];
  const float* v5  = (const float*)d_in[33];
  const float* ow  = (const float*)d_in[34];
  const float* ob  = (const float*)d_in[35];

  char* ws = (char*)d_ws;
  float* xg   = (float*)(ws);              // 512*127*64 f32      = 16,646,144 B
  char*  hb   = ws + 16646144;             // 512*128*192 f16 swz = 25,165,824 B
  char*  lwT  = ws + 41811968;             // 1024*192 f16 swz    =    393,216 B
  int*   idxb = (int*)(ws + 42205184);     // 512*127*5 i32       =  1,300,480 B
  float* gbuf = (float*)(ws + 43505664);   // 512*1024 f32        =  2,097,152 B
  float* c1   = (float*)(ws + 45602816);   // 512*512 f32         =  1,048,576 B
  float* c2   = (float*)(ws + 46651392);   // 512*256 f32         =    524,288 B

  hipLaunchKernelGGL(k0_prep, dim3(32), dim3(256), 0, stream, lw, lwT);
  hipLaunchKernelGGL(k1_conv, dim3(512), dim3(256), 0, stream,
                     pos, cw, cb, g1, b1, m1, v1, xg, hb);
  hipLaunchKernelGGL(k2_knn, dim3(512), dim3(128), 0, stream, xg, idxb);
  hipLaunchKernelGGL(k3_edge, dim3(512), dim3(256), 0, stream,
                     xg, idxb, ew, eb, g2, b2, m2, v2, hb);
  hipLaunchKernelGGL(k4_lin1, dim3(512), dim3(256), 0, stream,
                     hb, lwT, lb, g3, b3, m3, v3, gbuf);
  hipLaunchKernelGGL(k5_mlp, dim3(512), dim3(256), 4 * 1024 * 4, stream,
                     gbuf, m1w, m1b, g4, b4, m4, v4, c1, 1024, 512, 4);
  hipLaunchKernelGGL(k5_mlp, dim3(256), dim3(256), 4 * 512 * 4, stream,
                     c1, m2w, m2b, g5, b5, m5, v5, c2, 512, 256, 2);
  hipLaunchKernelGGL(k5c_out, dim3(4), dim3(256), 0, stream,
                     c2, ow, ob, (float*)d_out);
}

// Round 3
// 255.544 us; speedup vs baseline: 3.0237x; 1.1423x over previous
//
#include <hip/hip_runtime.h>

#define BB 512
#define LL 128
#define MM 127
#define EPS 1e-5f

typedef _Float16 half4 __attribute__((ext_vector_type(4)));
typedef _Float16 half8 __attribute__((ext_vector_type(8)));
typedef float f32x16 __attribute__((ext_vector_type(16)));

// hb layout: per batch b: 128 rows x 192 ch fp16, row pitch 384 B,
// in-row byte offset = (2*ch) ^ ((row&7)<<4)   (XOR swizzle, G4)
#define HB_PITCH 384
#define HB_BATCH 49152

// ---------------------------------------------------------------- K0: weight prep
// blocks 0..31: lwT[col][k] fp16 swizzled (lin1_w transpose).
// block 32:     ewT[col][k] fp16 swizzled; cols 0..127 = wd = top-bot, 128..255 = wb = bot.
__global__ __launch_bounds__(256) void k0_prep(
    const float* __restrict__ lw, char* __restrict__ lwT,
    const float* __restrict__ ew, char* __restrict__ ewT)
{
  int tid = threadIdx.x;
  if (blockIdx.x < 32) {
    int c0 = blockIdx.x * 32;
    __shared__ float wcol[192][32];
    for (int i = tid; i < 192 * 32; i += 256) {
      int k = i >> 5, c = i & 31;
      wcol[k][c] = lw[k * 1024 + c0 + c];
    }
    __syncthreads();
    for (int j = tid; j < 768; j += 256) {
      int kg = j >> 5, c = j & 31;
      half8 v;
#pragma unroll
      for (int jj = 0; jj < 8; jj++) v[jj] = (_Float16)wcol[kg * 8 + jj][c];
      int cc = c0 + c;
      *(half8*)(lwT + cc * HB_PITCH + ((kg * 16) ^ ((cc & 7) << 4))) = v;
    }
  } else {
    __shared__ float es[128][128];   // ew is 128x128 f32
    for (int i = tid; i < 128 * 128; i += 256) es[i >> 7][i & 127] = ew[i];
    __syncthreads();
    for (int i = tid; i < 256 * 8; i += 256) {
      int c = i >> 3, kg = i & 7;
      half8 v;
#pragma unroll
      for (int jj = 0; jj < 8; jj++) {
        int k = kg * 8 + jj;
        float val = (c < 128) ? (es[k][c] - es[64 + k][c]) : es[64 + k][c - 128];
        v[jj] = (_Float16)val;
      }
      *(half8*)(ewT + c * 128 + ((kg * 16) ^ ((c & 7) << 4))) = v;
    }
  }
}

// ---------------------------------------------------------------- K1: conv1d
__global__ __launch_bounds__(256) void k1_conv(
    const float* __restrict__ pos, const float* __restrict__ cw,
    const float* __restrict__ cb, const float* __restrict__ g1,
    const float* __restrict__ b1, const float* __restrict__ m1,
    const float* __restrict__ v1, float* __restrict__ xg,
    char* __restrict__ hb)
{
  int b = blockIdx.x;
  int tid = threadIdx.x;
  __shared__ float ps[LL * 3];
  __shared__ float fpad[MM + 4][6];
  __shared__ float ws[5 * 6 * 64];
  __shared__ float s1s[64], t1s[64];
  for (int i = tid; i < LL * 3; i += 256) ps[i] = pos[b * LL * 3 + i];
  for (int i = tid; i < 5 * 6 * 64; i += 256) ws[i] = cw[i];
  if (tid < 64) {
    float s = g1[tid] * rsqrtf(v1[tid] + EPS);
    s1s[tid] = s;
    t1s[tid] = (cb[tid] - m1[tid]) * s + b1[tid];
  }
  if (tid < 24) {
    int r = tid / 6, c = tid % 6;
    int rr = (r < 2) ? r : (MM + r);
    fpad[rr][c] = 0.f;
  }
  __syncthreads();
  for (int i = tid; i < MM * 6; i += 256) {
    int m = i / 6, c = i % 6;
    float v = (c < 3) ? (ps[(m + 1) * 3 + c] - ps[m * 3 + c]) : ps[m * 3 + c - 3];
    fpad[m + 2][c] = v;
  }
  __syncthreads();
  int orow = BB - 1 - b;
  char* hbb = hb + (size_t)orow * HB_BATCH;
  // zero fp16 pad row 127, ch 0..63 region (bytes [0,128))
  if (tid < 8) *(float4*)(hbb + 127 * HB_PITCH + tid * 16) = make_float4(0.f, 0.f, 0.f, 0.f);
  for (int o = tid; o < MM * 64; o += 256) {
    int m = o >> 6, c = o & 63;
    float af = 0.f, ab = 0.f;
#pragma unroll
    for (int t = 0; t < 5; t++) {
#pragma unroll
      for (int ci = 0; ci < 6; ci++) {
        float wv = ws[(t * 6 + ci) * 64 + c];
        af = fmaf(fpad[m + t][ci], wv, af);
        ab = fmaf(fpad[m + 4 - t][ci], wv, ab);
      }
    }
    float z = fmaxf(af, ab) * s1s[c] + t1s[c];
    float xv = fmaxf(z, 0.f);
    int p = MM - 1 - m;
    xg[(orow * MM + p) * 64 + c] = xv;
    *(_Float16*)(hbb + p * HB_PITCH + ((2 * c) ^ ((p & 7) << 4))) = (_Float16)xv;
  }
}

// ---------------------------------------------------------------- K2: kNN top-5
__global__ __launch_bounds__(128) void k2_knn(
    const float* __restrict__ xg, int* __restrict__ idxb)
{
  int b = blockIdx.x;
  int tid = threadIdx.x;
  __shared__ float xs[MM][64];
  __shared__ float sq[MM];
  const float* src = xg + b * MM * 64;
  for (int i = tid; i < MM * 64; i += 128) xs[i >> 6][i & 63] = src[i];
  __syncthreads();
  float xm[64];
  if (tid < MM) {
    float s = 0.f;
#pragma unroll
    for (int d = 0; d < 64; d++) { xm[d] = xs[tid][d]; s = fmaf(xm[d], xm[d], s); }
    sq[tid] = s;
  }
  __syncthreads();
  if (tid < MM) {
    float bs[5]; int bi[5];
#pragma unroll
    for (int k = 0; k < 5; k++) { bs[k] = 1e30f; bi[k] = 0; }
    for (int j = 0; j < MM; j++) {
      float dot = 0.f;
#pragma unroll
      for (int d = 0; d < 64; d++) dot = fmaf(xm[d], xs[j][d], dot);
      float sc = sq[j] - 2.f * dot;
      if (sc < bs[4]) {
        bs[4] = sc; bi[4] = j;
#pragma unroll
        for (int k = 3; k >= 0; k--) {
          if (bs[k + 1] < bs[k]) {
            float ts = bs[k]; bs[k] = bs[k + 1]; bs[k + 1] = ts;
            int ti = bi[k]; bi[k] = bi[k + 1]; bi[k + 1] = ti;
          }
        }
      }
    }
    int base = (b * MM + tid) * 5;
#pragma unroll
    for (int k = 0; k < 5; k++) idxb[base + k] = bi[k];
  }
}

// ---------------------------------------------------------------- K3: edge MLP via MFMA
// A = hb[b] ch0..63 (fp16 swizzled, global; 128x64). B = ewT (256 cols: wd|wb).
// Wave w owns cols w*32..+32 of both u (=xs@wd, kept in C-frags/registers) and
// vv (=xs@wb, stored LDS fp16). Gather: x2[p][c] = relu(max_k(u+vv[idx_k])+eb)*s2+t2
// -> fp16 scatter into hb ch 64..191. No A/W LDS staging (L1/L2 serve frags).
__global__ __launch_bounds__(256) void k3_edge(
    const int* __restrict__ idxb, const char* __restrict__ ewT,
    const float* __restrict__ eb, const float* __restrict__ g2,
    const float* __restrict__ b2, const float* __restrict__ m2,
    const float* __restrict__ v2, char* __restrict__ hb)
{
  int b = blockIdx.x;
  int tid = threadIdx.x;
  int w = tid >> 6, l = tid & 63;
  int lo = l & 31, hi = l >> 5;
  __shared__ _Float16 vvs[MM][136];   // pitch 272 B (68 dw == 4 mod 32: rows shift banks)
  __shared__ int idxs[MM * 5];
  char* hbb = hb + (size_t)b * HB_BATCH;

  for (int i = tid; i < MM * 5; i += 256) idxs[i] = idxb[b * MM * 5 + i];
  // zero pad row 127, ch 64..191 (bytes [128,384)) for k4
  if (tid < 16) *(float4*)(hbb + 127 * HB_PITCH + 128 + tid * 16) = make_float4(0.f, 0.f, 0.f, 0.f);

  // A fragments straight from global hb (rows rt*32+lo, k = ks*16 + hi*8 .. +8)
  half8 af[4][4];
#pragma unroll
  for (int rt = 0; rt < 4; rt++) {
    int row = rt * 32 + lo;
    const char* rb = hbb + row * HB_PITCH;
    int sz = (row & 7) << 4;
#pragma unroll
    for (int ks = 0; ks < 4; ks++)
      af[rt][ks] = *(const half8*)(rb + ((ks * 32 + hi * 16) ^ sz));
  }
  // B fragments from global ewT: u col = cu, vv col = 128 + cu  ((col&7) identical)
  int cu = w * 32 + lo;
  int swzW = (cu & 7) << 4;
  const char* wu = ewT + cu * 128;
  const char* wv = ewT + (128 + cu) * 128;
  half8 bu[4], bv[4];
#pragma unroll
  for (int ks = 0; ks < 4; ks++) {
    int off = (ks * 32 + hi * 16) ^ swzW;
    bu[ks] = *(const half8*)(wu + off);
    bv[ks] = *(const half8*)(wv + off);
  }
  f32x16 accu[4], accv[4];
#pragma unroll
  for (int rt = 0; rt < 4; rt++)
#pragma unroll
    for (int r = 0; r < 16; r++) { accu[rt][r] = 0.f; accv[rt][r] = 0.f; }
#pragma unroll
  for (int ks = 0; ks < 4; ks++)
#pragma unroll
    for (int rt = 0; rt < 4; rt++) {
      accu[rt] = __builtin_amdgcn_mfma_f32_32x32x16_f16(af[rt][ks], bu[ks], accu[rt], 0, 0, 0);
      accv[rt] = __builtin_amdgcn_mfma_f32_32x32x16_f16(af[rt][ks], bv[ks], accv[rt], 0, 0, 0);
    }
  // vv -> LDS (C layout: col=lane&31, row=(r&3)+8*(r>>2)+4*hi, m74/m101)
#pragma unroll
  for (int rt = 0; rt < 4; rt++)
#pragma unroll
    for (int r = 0; r < 16; r++) {
      int p = rt * 32 + (r & 3) + 8 * (r >> 2) + 4 * hi;
      if (p < MM) vvs[p][cu] = (_Float16)accv[rt][r];
    }
  __syncthreads();
  float ebv = eb[cu];
  float s2 = g2[cu] * rsqrtf(v2[cu] + EPS);
  float t2 = b2[cu] - m2[cu] * s2;
#pragma unroll
  for (int rt = 0; rt < 4; rt++)
#pragma unroll
    for (int r = 0; r < 16; r++) {
      int p = rt * 32 + (r & 3) + 8 * (r >> 2) + 4 * hi;
      if (p >= MM) continue;
      const int* ip = &idxs[p * 5];
      float u = accu[rt][r];
      float mx = -1e30f;
#pragma unroll
      for (int k = 0; k < 5; k++)
        mx = fmaxf(mx, u + (float)vvs[ip[k]][cu]);
      float o = fmaxf(mx + ebv, 0.f) * s2 + t2;
      *(_Float16*)(hbb + p * HB_PITCH + ((128 + 2 * cu) ^ ((p & 7) << 4))) = (_Float16)o;
    }
}

// ---------------------------------------------------------------- K4: lin1 via MFMA + max over M
__global__ __launch_bounds__(256, 1) void k4_lin1(
    const char* __restrict__ hb, const char* __restrict__ lwT,
    const float* __restrict__ lb, const float* __restrict__ g3,
    const float* __restrict__ b3, const float* __restrict__ m3,
    const float* __restrict__ v3, float* __restrict__ gout)
{
  int b = blockIdx.x;
  int tid = threadIdx.x;
  int w = tid >> 6, l = tid & 63;
  int lo = l & 31, hi = l >> 5;
  int swz = (l & 7) << 4;
  __shared__ __align__(16) char sA[HB_BATCH];
  __shared__ __align__(16) char sB[2][HB_BATCH];

  {
    const char* gA = hb + (size_t)b * HB_BATCH;
    float4 t[12];
#pragma unroll
    for (int i = 0; i < 12; i++) t[i] = *(const float4*)(gA + (i * 256 + tid) * 16);
#pragma unroll
    for (int i = 0; i < 12; i++) *(float4*)(sA + (i * 256 + tid) * 16) = t[i];
  }
  {
    float4 t[12];
#pragma unroll
    for (int i = 0; i < 12; i++) t[i] = *(const float4*)(lwT + (i * 256 + tid) * 16);
#pragma unroll
    for (int i = 0; i < 12; i++) *(float4*)(sB[0] + (i * 256 + tid) * 16) = t[i];
  }
  __syncthreads();

  half8 af[4][12];
#pragma unroll
  for (int rt = 0; rt < 4; rt++) {
    const char* rbase = sA + (rt * 32 + lo) * HB_PITCH;
#pragma unroll
    for (int ks = 0; ks < 12; ks++)
      af[rt][ks] = *(const half8*)(rbase + ((ks * 32 + hi * 16) ^ swz));
  }

  int colc = w * 32 + lo;
  float4 pre[12];
  for (int c = 0; c < 8; c++) {
    if (c < 7) {
      const char* gB = lwT + (size_t)(c + 1) * HB_BATCH;
#pragma unroll
      for (int i = 0; i < 12; i++) pre[i] = *(const float4*)(gB + (i * 256 + tid) * 16);
    }
    f32x16 acc[4];
#pragma unroll
    for (int rt = 0; rt < 4; rt++)
#pragma unroll
      for (int r = 0; r < 16; r++) acc[rt][r] = 0.f;
    const char* cbase = sB[c & 1] + colc * HB_PITCH;
#pragma unroll
    for (int ks = 0; ks < 12; ks++) {
      half8 bf = *(const half8*)(cbase + ((ks * 32 + hi * 16) ^ swz));
#pragma unroll
      for (int rt = 0; rt < 4; rt++)
        acc[rt] = __builtin_amdgcn_mfma_f32_32x32x16_f16(af[rt][ks], bf, acc[rt], 0, 0, 0);
    }
    int col = c * 128 + colc;
    float bias = lb[col];
    float rm = 0.f;
#pragma unroll
    for (int rt = 0; rt < 4; rt++) {
#pragma unroll
      for (int r = 0; r < 16; r++) {
        float v = fmaxf(acc[rt][r] + bias, 0.f);
        if (rt == 3 && r == 15) v = hi ? 0.f : v;
        rm = fmaxf(rm, v);
      }
    }
    rm = fmaxf(rm, __shfl_xor(rm, 32));
    if (hi == 0) {
      float s = g3[col] * rsqrtf(v3[col] + EPS);
      float t = b3[col] - m3[col] * s;
      gout[b * 1024 + col] = rm * s + t;
    }
    if (c < 7) {
      char* db = sB[(c + 1) & 1];
#pragma unroll
      for (int i = 0; i < 12; i++) *(float4*)(db + (i * 256 + tid) * 16) = pre[i];
    }
    __syncthreads();
  }
}

// ---------------------------------------------------------------- K5: head MLP layers
__global__ __launch_bounds__(256) void k5_mlp(
    const float* __restrict__ in, const float* __restrict__ w,
    const float* __restrict__ bias, const float* __restrict__ gg,
    const float* __restrict__ bbp, const float* __restrict__ mmp,
    const float* __restrict__ vvp, float* __restrict__ out,
    int K, int N, int ctiles)
{
  int bid = blockIdx.x;
  int rg = bid / ctiles, ct = bid % ctiles;
  int tid = threadIdx.x;
  int c = tid & 127, rh = tid >> 7;
  int col = ct * 128 + c;
  extern __shared__ float grows[];
  for (int i = tid; i < 4 * K; i += 256) grows[i] = in[rg * 4 * K + i];
  __syncthreads();
  float acc0 = 0.f, acc1 = 0.f;
  for (int d4 = 0; d4 < K / 4; d4++) {
    float4 ga = *reinterpret_cast<const float4*>(&grows[rh * K + d4 * 4]);
    float4 gb = *reinterpret_cast<const float4*>(&grows[(rh + 2) * K + d4 * 4]);
    float gaa[4] = {ga.x, ga.y, ga.z, ga.w};
    float gba[4] = {gb.x, gb.y, gb.z, gb.w};
#pragma unroll
    for (int dd = 0; dd < 4; dd++) {
      float wv = w[(d4 * 4 + dd) * N + col];
      acc0 = fmaf(gaa[dd], wv, acc0);
      acc1 = fmaf(gba[dd], wv, acc1);
    }
  }
  float s = gg[col] * rsqrtf(vvp[col] + EPS);
  float t = bbp[col] - mmp[col] * s;
  float bv = bias[col];
  int r0 = rg * 4;
  out[(r0 + rh) * N + col] = fmaxf(acc0 + bv, 0.f) * s + t;
  out[(r0 + rh + 2) * N + col] = fmaxf(acc1 + bv, 0.f) * s + t;
}

// ---------------------------------------------------------------- K5c: final 256->2
__global__ __launch_bounds__(256) void k5c_out(
    const float* __restrict__ c2, const float* __restrict__ ow,
    const float* __restrict__ ob, float* __restrict__ out)
{
  int t = blockIdx.x * 256 + threadIdx.x;
  int r = t >> 1, c = t & 1;
  float acc = 0.f;
  for (int d = 0; d < 256; d++) acc = fmaf(c2[r * 256 + d], ow[d * 2 + c], acc);
  out[t] = acc + ob[c];
}

extern "C" void kernel_launch(void* const* d_in, const int* in_sizes, int n_in,
                              void* d_out, int out_size, void* d_ws, size_t ws_size,
                              hipStream_t stream)
{
  const float* pos = (const float*)d_in[0];
  const float* cw  = (const float*)d_in[4];
  const float* cb  = (const float*)d_in[5];
  const float* g1  = (const float*)d_in[6];
  const float* b1  = (const float*)d_in[7];
  const float* m1  = (const float*)d_in[8];
  const float* v1  = (const float*)d_in[9];
  const float* ew  = (const float*)d_in[10];
  const float* eb  = (const float*)d_in[11];
  const float* g2  = (const float*)d_in[12];
  const float* b2  = (const float*)d_in[13];
  const float* m2  = (const float*)d_in[14];
  const float* v2  = (const float*)d_in[15];
  const float* lw  = (const float*)d_in[16];
  const float* lb  = (const float*)d_in[17];
  const float* g3  = (const float*)d_in[18];
  const float* b3  = (const float*)d_in[19];
  const float* m3  = (const float*)d_in[20];
  const float* v3  = (const float*)d_in[21];
  const float* m1w = (const float*)d_in[22];
  const float* m1b = (const float*)d_in[23];
  const float* g4  = (const float*)d_in[24];
  const float* b4  = (const float*)d_in[25];
  const float* m4  = (const float*)d_in[26];
  const float* v4  = (const float*)d_in[27];
  const float* m2w = (const float*)d_in[28];
  const float* m2b = (const float*)d_in[29];
  const float* g5  = (const float*)d_in[30];
  const float* b5  = (const float*)d_in[31];
  const float* m5  = (const float*)d_in[32];
  const float* v5  = (const float*)d_in[33];
  const float* ow  = (const float*)d_in[34];
  const float* ob  = (const float*)d_in[35];

  char* ws = (char*)d_ws;
  float* xg   = (float*)(ws);              // 512*127*64 f32      = 16,646,144 B
  char*  hb   = ws + 16646144;             // 512*128*192 f16 swz = 25,165,824 B
  char*  lwT  = ws + 41811968;             // 1024*192 f16 swz    =    393,216 B
  char*  ewT  = ws + 42205184;             // 256*64 f16 swz      =     32,768 B
  int*   idxb = (int*)(ws + 42237952);     // 512*127*5 i32       =  1,300,480 B
  float* gbuf = (float*)(ws + 43538432);   // 512*1024 f32        =  2,097,152 B
  float* c1   = (float*)(ws + 45635584);   // 512*512 f32         =  1,048,576 B
  float* c2   = (float*)(ws + 46684160);   // 512*256 f32         =    524,288 B

  hipLaunchKernelGGL(k0_prep, dim3(33), dim3(256), 0, stream, lw, lwT, ew, ewT);
  hipLaunchKernelGGL(k1_conv, dim3(512), dim3(256), 0, stream,
                     pos, cw, cb, g1, b1, m1, v1, xg, hb);
  hipLaunchKernelGGL(k2_knn, dim3(512), dim3(128), 0, stream, xg, idxb);
  hipLaunchKernelGGL(k3_edge, dim3(512), dim3(256), 0, stream,
                     idxb, ewT, eb, g2, b2, m2, v2, hb);
  hipLaunchKernelGGL(k4_lin1, dim3(512), dim3(256), 0, stream,
                     hb, lwT, lb, g3, b3, m3, v3, gbuf);
  hipLaunchKernelGGL(k5_mlp, dim3(512), dim3(256), 4 * 1024 * 4, stream,
                     gbuf, m1w, m1b, g4, b4, m4, v4, c1, 1024, 512, 4);
  hipLaunchKernelGGL(k5_mlp, dim3(256), dim3(256), 4 * 512 * 4, stream,
                     c1, m2w, m2b, g5, b5, m5, v5, c2, 512, 256, 2);
  hipLaunchKernelGGL(k5c_out, dim3(4), dim3(256), 0, stream,
                     c2, ow, ob, (float*)d_out);
}